// Round 14
// baseline (2642.045 us; speedup 1.0000x reference)
//
#include <hip/hip_runtime.h>

typedef unsigned short u16;
typedef __attribute__((ext_vector_type(8))) short short8;
typedef __attribute__((ext_vector_type(4))) float f32x4;
typedef __attribute__((ext_vector_type(4))) unsigned int u32x4;

#define B_  32
#define T_  128
#define N_  196
#define D_  768
#define E_  256
#define H_  512
#define V_  10000
#define G4H 2048
#define NBLK 256
#define BH  (B_ * H_)
#define BD  (B_ * D_)

// workspace offsets (bytes), all 256-aligned
#define O_ENCBF 0UL            // 9,633,792   enc bf16 [32][196][768]
#define O_WHT   9633792UL      // 524,288     WhT bf16 [col][k]
#define O_WHHT  10158080UL     // 2,097,152   WhhT [2048 col][512 k]
#define O_WIHDT 12255232UL     // 3,145,728   WihDT[2048 col][768 d]
#define O_KE    15400960UL     // 6,422,528   Ke bf16 [6272][512]
#define O_GEMB  21823488UL     // 16,777,216  g_emb bf16 [t][2048 col][32 b]
#define O_BSUM  38600704UL     // 8,192       bih+bhh
#define O_CT    38608896UL     // 65,536      c0 f32 [32][512]
#define O_HIST  38674432UL     // 4,194,304   h_hist bf16 [b*T+t][512]
#define O_HX2   42868736UL     // 65,536      h bf16 [2][32][512]
#define O_HWX   42934272UL     // 65,536      hw f32 [32][512]
#define O_CTXA  42999808UL     // 196,608     ctxAcc f32 [2][32][768]
#define O_DEN   43196416UL     // 256         denom f32 [2][32]
#define O_BARS  43196672UL     // 2,048       16 arrival lines x 128B
#define O_REL   43198720UL     // 32,768      256 release lines x 128B

__device__ __forceinline__ float b2f(u16 u) {
  union { unsigned i; float f; } c; c.i = ((unsigned)u) << 16; return c.f;
}
__device__ __forceinline__ u16 f2b(float f) {   // RNE f32->bf16
  unsigned u = __float_as_uint(f);
  unsigned r = (u + 0x7fffu + ((u >> 16) & 1u)) >> 16;
  return (u16)r;
}
__device__ __forceinline__ float fast_tanh(float x) {
  float e = __expf(2.f * x);
  return 1.f - 2.f * __builtin_amdgcn_rcpf(e + 1.f);
}
__device__ __forceinline__ float sigm(float x) {
  return __builtin_amdgcn_rcpf(1.f + __expf(-x));
}
__device__ __forceinline__ float wred_sum(float x) {
  #pragma unroll
  for (int o = 32; o; o >>= 1) x += __shfl_xor(x, o, 64);
  return x;
}

// ---- L2-bypass (device-coherent) ops ----
__device__ __forceinline__ float ld_bypass_f32(const float* p) {
  float v;
  asm volatile("global_load_dword %0, %1, off sc0 sc1\n\ts_waitcnt vmcnt(0)"
               : "=v"(v) : "v"(p) : "memory");
  return v;
}
__device__ __forceinline__ unsigned ld_bypass_u32(const unsigned* p) {
  unsigned v;
  asm volatile("global_load_dword %0, %1, off sc0 sc1\n\ts_waitcnt vmcnt(0)"
               : "=v"(v) : "v"(p) : "memory");
  return v;
}
__device__ __forceinline__ void ld2_bypass(const void* p0, const void* p1,
                                           u32x4& a, u32x4& b) {
  asm volatile(
    "global_load_dwordx4 %0, %2, off sc0 sc1\n\t"
    "global_load_dwordx4 %1, %3, off sc0 sc1\n\t"
    "s_waitcnt vmcnt(0)"
    : "=&v"(a), "=&v"(b) : "v"(p0), "v"(p1) : "memory");
}
// 6 x4-loads (ctxAcc f32) + 1 f32 (denom), single wait
__device__ __forceinline__ void ld6_1_bypass(
    const void* p0, const void* p1, const void* p2, const void* p3,
    const void* p4, const void* p5, const void* pd,
    u32x4& a, u32x4& b, u32x4& c, u32x4& d, u32x4& e, u32x4& f, float& dv) {
  asm volatile(
    "global_load_dwordx4 %0, %7, off sc0 sc1\n\t"
    "global_load_dwordx4 %1, %8, off sc0 sc1\n\t"
    "global_load_dwordx4 %2, %9, off sc0 sc1\n\t"
    "global_load_dwordx4 %3, %10, off sc0 sc1\n\t"
    "global_load_dwordx4 %4, %11, off sc0 sc1\n\t"
    "global_load_dwordx4 %5, %12, off sc0 sc1\n\t"
    "global_load_dword %6, %13, off sc0 sc1\n\t"
    "s_waitcnt vmcnt(0)"
    : "=&v"(a), "=&v"(b), "=&v"(c), "=&v"(d), "=&v"(e), "=&v"(f), "=&v"(dv)
    : "v"(p0), "v"(p1), "v"(p2), "v"(p3), "v"(p4), "v"(p5), "v"(pd)
    : "memory");
}
__device__ __forceinline__ void st_bypass_f32(float* p, float v) {
  asm volatile("global_store_dword %0, %1, off sc0 sc1" :: "v"(p), "v"(v) : "memory");
}
__device__ __forceinline__ void st_bypass_u32(unsigned* p, unsigned v) {
  asm volatile("global_store_dword %0, %1, off sc0 sc1" :: "v"(p), "v"(v) : "memory");
}
__device__ __forceinline__ void st_bypass_u16(u16* p, u16 v) {
  unsigned vv = v;
  asm volatile("global_store_short %0, %1, off sc0 sc1" :: "v"(p), "v"(vv) : "memory");
}

__device__ __forceinline__ unsigned bar_sum16(const unsigned* p) {
  unsigned a0,a1,a2,a3,a4,a5,a6,a7,a8,a9,a10,a11,a12,a13,a14,a15;
  asm volatile(
    "global_load_dword %0, %16, off sc0 sc1\n\t"
    "global_load_dword %1, %16, off offset:128 sc0 sc1\n\t"
    "global_load_dword %2, %16, off offset:256 sc0 sc1\n\t"
    "global_load_dword %3, %16, off offset:384 sc0 sc1\n\t"
    "global_load_dword %4, %16, off offset:512 sc0 sc1\n\t"
    "global_load_dword %5, %16, off offset:640 sc0 sc1\n\t"
    "global_load_dword %6, %16, off offset:768 sc0 sc1\n\t"
    "global_load_dword %7, %16, off offset:896 sc0 sc1\n\t"
    "global_load_dword %8, %16, off offset:1024 sc0 sc1\n\t"
    "global_load_dword %9, %16, off offset:1152 sc0 sc1\n\t"
    "global_load_dword %10, %16, off offset:1280 sc0 sc1\n\t"
    "global_load_dword %11, %16, off offset:1408 sc0 sc1\n\t"
    "global_load_dword %12, %16, off offset:1536 sc0 sc1\n\t"
    "global_load_dword %13, %16, off offset:1664 sc0 sc1\n\t"
    "global_load_dword %14, %16, off offset:1792 sc0 sc1\n\t"
    "global_load_dword %15, %16, off offset:1920 sc0 sc1\n\t"
    "s_waitcnt vmcnt(0)"
    : "=&v"(a0), "=&v"(a1), "=&v"(a2), "=&v"(a3), "=&v"(a4), "=&v"(a5),
      "=&v"(a6), "=&v"(a7), "=&v"(a8), "=&v"(a9), "=&v"(a10), "=&v"(a11),
      "=&v"(a12), "=&v"(a13), "=&v"(a14), "=&v"(a15)
    : "v"(p) : "memory");
  return ((a0+a1)+(a2+a3)) + ((a4+a5)+(a6+a7)) +
         ((a8+a9)+(a10+a11)) + ((a12+a13)+(a14+a15));
}

// plain master-detect barrier (used for bar2)
__device__ __forceinline__ void gridbar(unsigned* bars, unsigned* rel,
                                        int bid, unsigned target) {
  __syncthreads();
  if (bid == 0) {
    if (threadIdx.x == 0) {
      asm volatile("s_waitcnt vmcnt(0) lgkmcnt(0)" ::: "memory");
      __hip_atomic_fetch_add(bars, 1u, __ATOMIC_RELAXED, __HIP_MEMORY_SCOPE_AGENT);
      while (bar_sum16(bars) < target) __builtin_amdgcn_s_sleep(1);
    }
    __syncthreads();
    if (threadIdx.x < NBLK) st_bypass_u32(rel + (size_t)threadIdx.x * 32, target);
  } else {
    if (threadIdx.x == 0) {
      asm volatile("s_waitcnt vmcnt(0) lgkmcnt(0)" ::: "memory");
      __hip_atomic_fetch_add(bars + (size_t)(bid & 15) * 32, 1u,
                             __ATOMIC_RELAXED, __HIP_MEMORY_SCOPE_AGENT);
      while (ld_bypass_u32(rel + (size_t)bid * 32) < target)
        __builtin_amdgcn_s_sleep(2);
    }
    __syncthreads();
  }
}

// ---------------- prep kernels ----------------

__global__ void conv_bf(const float* __restrict__ in, u16* __restrict__ out, int n) {
  int i = blockIdx.x * blockDim.x + threadIdx.x;
  int st = gridDim.x * blockDim.x;
  for (; i < n; i += st) out[i] = f2b(in[i]);
}

__global__ void bsum_k(const float* __restrict__ a, const float* __restrict__ b,
                       float* __restrict__ o, int n) {
  int i = blockIdx.x * blockDim.x + threadIdx.x;
  if (i < n) o[i] = a[i] + b[i];
}

// out[c][r] = bf16(in[r][c]); in is R x C
__global__ void transpose_bf(const float* __restrict__ in, u16* __restrict__ out, int R, int C) {
  __shared__ float tl[64][65];
  int tid = threadIdx.x;
  int tc0 = blockIdx.x * 64, tr0 = blockIdx.y * 64;
  int cc = tid & 63;
  for (int rr = tid >> 6; rr < 64; rr += 4) {
    int rg = tr0 + rr, cg = tc0 + cc;
    tl[rr][cc] = (rg < R && cg < C) ? in[(size_t)rg * C + cg] : 0.f;
  }
  __syncthreads();
  int rr = tid & 63;
  for (int c2 = tid >> 6; c2 < 64; c2 += 4) {
    int cg = tc0 + c2, rg = tr0 + rr;
    if (cg < C && rg < R) out[(size_t)cg * R + rg] = f2b(tl[rr][c2]);
  }
}

// h0/c0 (writes h bf16 into exchange buffer 0)
__global__ __launch_bounds__(512) void init_hc(
    const float* __restrict__ enc, const float* __restrict__ W2h,
    const float* __restrict__ b2h, const float* __restrict__ W2c,
    const float* __restrict__ b2c, u16* __restrict__ hx2, float* __restrict__ cT)
{
  __shared__ float pool[D_];
  int b = blockIdx.x, tid = threadIdx.x;
  for (int d = tid; d < D_; d += 512) {
    float s = 0.f;
    const float* ep = enc + (size_t)b * N_ * D_ + d;
    for (int n = 0; n < N_; ++n) s += ep[(size_t)n * D_];
    pool[d] = s * (1.f / 196.f);
  }
  __syncthreads();
  float a = b2h[tid], a2 = b2c[tid];
  #pragma unroll 4
  for (int d = 0; d < D_; ++d) {
    float pv = pool[d];
    a  += pv * W2h[d * H_ + tid];
    a2 += pv * W2c[d * H_ + tid];
  }
  hx2[b * H_ + tid] = f2b(fast_tanh(a));
  cT[b * H_ + tid] = fast_tanh(a2);
}

// ---------------- MFMA GEMM ----------------
// AMODE: 0 = A bf16; 1 = A f32 gathered via xidx
// OUTMODE: 0 = f32 row-major; 1 = bf16 row-major; 3 = bf16 scatter [t][col][b]
template<int AMODE, int OUTMODE, int BIAS>
__global__ __launch_bounds__(256) void gemm2(
    const void* __restrict__ Av, const float* __restrict__ Bf,
    const int* __restrict__ xidx, void* __restrict__ Cv,
    const float* __restrict__ bias, int M, int N, int K, int lda)
{
  __shared__ __align__(16) u16 Al[128][72];
  __shared__ __align__(16) u16 Bl[128][72];
  const int tid = threadIdx.x;
  const int tm0 = blockIdx.y * 128, tn0 = blockIdx.x * 128;
  const int wv = tid >> 6, lane = tid & 63;
  const int wr = wv >> 1, wc = wv & 1;
  f32x4 acc[4][4] = {};
  const int r = tid >> 1, cb = (tid & 1) * 32;
  const int bkr = tid >> 5;
  const int bnc = (tid & 31) * 4;
  for (int k0 = 0; k0 < K; k0 += 64) {
    int rm = tm0 + r; if (rm >= M) rm = M - 1;
    if (AMODE == 0) {
      const u16* gp = (const u16*)Av + (size_t)rm * lda + k0 + cb;
      #pragma unroll
      for (int u = 0; u < 4; ++u)
        *(short8*)&Al[r][cb + u * 8] = *(const short8*)(gp + u * 8);
    } else {
      const float* gp = (const float*)Av + (size_t)xidx[rm] * lda + k0 + cb;
      #pragma unroll
      for (int u = 0; u < 4; ++u) {
        f32x4 a0 = *(const f32x4*)(gp + u * 8);
        f32x4 a1 = *(const f32x4*)(gp + u * 8 + 4);
        Al[r][cb + u * 8 + 0] = f2b(a0[0]); Al[r][cb + u * 8 + 1] = f2b(a0[1]);
        Al[r][cb + u * 8 + 2] = f2b(a0[2]); Al[r][cb + u * 8 + 3] = f2b(a0[3]);
        Al[r][cb + u * 8 + 4] = f2b(a1[0]); Al[r][cb + u * 8 + 5] = f2b(a1[1]);
        Al[r][cb + u * 8 + 6] = f2b(a1[2]); Al[r][cb + u * 8 + 7] = f2b(a1[3]);
      }
    }
    {
      int ncc = tn0 + bnc; if (ncc > N - 4) ncc = N - 4;
      #pragma unroll
      for (int u = 0; u < 8; ++u) {
        int kr = bkr + u * 8;
        const float* bp = Bf + (size_t)(k0 + kr) * N + ncc;
        f32x4 bv = *(const f32x4*)bp;
        #pragma unroll
        for (int j = 0; j < 4; ++j) Bl[bnc + j][kr] = f2b(bv[j]);
      }
    }
    __syncthreads();
    #pragma unroll
    for (int kk = 0; kk < 64; kk += 32) {
      short8 af[4], bfv[4];
      #pragma unroll
      for (int i = 0; i < 4; ++i)
        af[i] = *(const short8*)&Al[wr * 64 + i * 16 + (lane & 15)][kk + (lane >> 4) * 8];
      #pragma unroll
      for (int j = 0; j < 4; ++j)
        bfv[j] = *(const short8*)&Bl[wc * 64 + j * 16 + (lane & 15)][kk + (lane >> 4) * 8];
      #pragma unroll
      for (int i = 0; i < 4; ++i)
        #pragma unroll
        for (int j = 0; j < 4; ++j)
          acc[i][j] = __builtin_amdgcn_mfma_f32_16x16x32_bf16(af[i], bfv[j], acc[i][j], 0, 0, 0);
    }
    __syncthreads();
  }
  #pragma unroll
  for (int i = 0; i < 4; ++i) {
    int row0 = tm0 + wr * 64 + i * 16 + (lane >> 4) * 4;
    #pragma unroll
    for (int j = 0; j < 4; ++j) {
      int col = tn0 + wc * 64 + j * 16 + (lane & 15);
      if (col < N) {
        float bs = BIAS ? bias[col] : 0.f;
        #pragma unroll
        for (int rr2 = 0; rr2 < 4; ++rr2) {
          int row = row0 + rr2;
          if (row < M) {
            float val = acc[i][j][rr2] + bs;
            if (OUTMODE == 0) ((float*)Cv)[(size_t)row * N + col] = val;
            else if (OUTMODE == 1) ((u16*)Cv)[(size_t)row * N + col] = f2b(val);
            else {
              int tt = row & 127, bb = row >> 7;
              ((u16*)Cv)[((size_t)tt * G4H + col) * 32 + bb] = f2b(val);
            }
          }
        }
      }
    }
  }
}

// ---------------- persistent 3-phase recurrent kernel ----------------
// 256 blocks x 512.
// Attention role: (b = bid>>3, s8 = bid&7): scores for n-slice s8.
// hw role: blocks with (bid&3)==0 compute hw tile [16b x 16c], ctile=(bid>>2)&31.
// Gate role: (bh = bid>>7, hb4 = bid&127): 16 gate cols for 16 b's, MFMA.
// All loop-invariant weights in registers; gate-MFMA split across bar1 window;
// ctxAcc/denom double-buffered so zeroing hides in bar3 window.
__global__ __launch_bounds__(512, 1) void recur8(
    const u16* __restrict__ enc_bf, const int* __restrict__ mask,
    const u16* __restrict__ Ke, const u16* __restrict__ WhT,
    const float* __restrict__ vvec, const u16* __restrict__ WhhT,
    const u16* __restrict__ WihDT, const u16* __restrict__ g_emb,
    const float* __restrict__ cT0,
    u16* hx2, float* hwx, float* ctxAcc, float* denom,
    u16* h_hist, float* out_h, float* out_c, unsigned* bars, unsigned* rel)
{
  __shared__ u32x4 hst16[64 * 16];       // h bf16 chunks [kc][16b], 16KB
  __shared__ union {
    struct { float hw8[512]; float e[32]; } p2;               // 2.2KB
    struct { u32x4 ctx16[96 * 16]; f32x4 part3[8][69]; } p3;  // ~33.4KB
  } su;
  __shared__ float gpre[16][16];
  __shared__ float cfl[4][16];     // persistent c state
  __shared__ float maskf[32];      // persistent mask slice

  const int bid = blockIdx.x, tid = threadIdx.x;
  const int lane = tid & 63, wvx = tid >> 6;
  // attention role
  const int b = bid >> 3, s8 = bid & 7;
  const int n0 = s8 * 25;
  const int nmax = min(25, N_ - n0);
  // gate role
  const int bh = bid >> 7, hb4 = bid & 127;
  const int b_base = bh * 16, hx4 = hb4 * 4;
  const int n16 = lane & 15, kh = lane >> 4;
  const int gcol = (n16 >> 2) * H_ + hx4 + (n16 & 3);
  // hw role
  const bool is_hw = (bid & 3) == 0;
  const int c0 = ((bid >> 2) & 31) * 16;
  // staging role
  const int bl = tid & 15, kc0 = tid >> 4;   // kc0 in [0,32)
  // readout role (tid<256)
  const int ro = tid & 15, co = tid >> 4;

  float vreg[8];
  #pragma unroll
  for (int j = 0; j < 8; ++j) vreg[j] = vvec[lane * 8 + j];
  if (tid < nmax) maskf[tid] = (mask[b * N_ + n0 + tid] == 0) ? 0.f : 1.f;
  if (tid < 64) cfl[tid >> 4][tid & 15] =
      cT0[(b_base + (tid & 15)) * H_ + hx4 + (tid >> 4)];

  // loop-invariant register weights
  short8 wf[5];                 // gate-weight fragments
  #pragma unroll
  for (int i = 0; i < 5; ++i) {
    int ks = wvx * 5 + i;
    if (ks < 16) wf[i] = *(const short8*)(WhhT + (size_t)gcol * H_ + ks * 32 + kh * 8);
    else         wf[i] = *(const short8*)(WihDT + (size_t)gcol * D_ + (ks - 16) * 32 + kh * 8);
  }
  short8 kvp[4];                // Ke rows for this lane / n-slice
  #pragma unroll
  for (int i = 0; i < 4; ++i) {
    int nn = wvx + i * 8; if (nn >= nmax) nn = nmax - 1;
    kvp[i] = *(const short8*)(Ke + ((size_t)(b * N_ + n0 + nn)) * H_ + lane * 8);
  }
  __syncthreads();

  unsigned tgt = 0;
  for (int t = 0; t < T_; ++t) {
    const int rb = t & 1, wb = rb ^ 1;
    const int cbuf = t & 1, nbuf = cbuf ^ 1;
    // ============ Phase 1: stage hst16; hw tiles via MFMA ============
    {
      const u16* hp = hx2 + (size_t)rb * BH + (b_base + bl) * H_;
      u32x4 v0, v1;
      ld2_bypass(hp + kc0 * 8, hp + (kc0 + 32) * 8, v0, v1);
      hst16[(kc0     ) * 16 + bl] = v0;
      hst16[(kc0 + 32) * 16 + bl] = v1;
    }
    __syncthreads();
    if (is_hw) {
      f32x4 hwacc = {0.f, 0.f, 0.f, 0.f};
      #pragma unroll
      for (int ks = 0; ks < 16; ++ks) {
        short8 bfrag = *(const short8*)(WhT + (size_t)(c0 + n16) * H_ + ks * 32 + kh * 8);
        hwacc = __builtin_amdgcn_mfma_f32_16x16x32_bf16(
            *(const short8*)&hst16[(ks * 4 + kh) * 16 + n16], bfrag, hwacc, 0, 0, 0);
      }
      #pragma unroll
      for (int j = 0; j < 4; ++j)
        st_bypass_f32(hwx + (size_t)(b_base + kh * 4 + j) * H_ + c0 + n16, hwacc[j]);
    }
    // ---- bar1 (arrive -> hidden work: Whh-half MFMA + g_emb prefetch -> wait)
    tgt += NBLK;
    f32x4 gacc = {0.f, 0.f, 0.f, 0.f};
    float ge_pf = 0.f;
    __syncthreads();
    if (tid == 0) {
      asm volatile("s_waitcnt vmcnt(0) lgkmcnt(0)" ::: "memory");
      __hip_atomic_fetch_add(bars + (size_t)(bid & 15) * 32, 1u,
                             __ATOMIC_RELAXED, __HIP_MEMORY_SCOPE_AGENT);
    }
    if (bid == 0) {
      if (tid == 0) { while (bar_sum16(bars) < tgt) __builtin_amdgcn_s_sleep(1); }
      __syncthreads();
      if (tid < NBLK) st_bypass_u32(rel + (size_t)tid * 32, tgt);
      #pragma unroll
      for (int i = 0; i < 5; ++i) {
        int ks = wvx * 5 + i;
        if (ks < 16)
          gacc = __builtin_amdgcn_mfma_f32_16x16x32_bf16(
              *(const short8*)&hst16[(ks * 4 + kh) * 16 + n16], wf[i], gacc, 0, 0, 0);
      }
      if (tid < 256) {
        int gco = (co >> 2) * H_ + hx4 + (co & 3);
        ge_pf = b2f(g_emb[((size_t)t * G4H + gco) * 32 + (b_base + ro)]);
      }
    } else {
      #pragma unroll
      for (int i = 0; i < 5; ++i) {
        int ks = wvx * 5 + i;
        if (ks < 16)
          gacc = __builtin_amdgcn_mfma_f32_16x16x32_bf16(
              *(const short8*)&hst16[(ks * 4 + kh) * 16 + n16], wf[i], gacc, 0, 0, 0);
      }
      if (tid < 256) {
        int gco = (co >> 2) * H_ + hx4 + (co & 3);
        ge_pf = b2f(g_emb[((size_t)t * G4H + gco) * 32 + (b_base + ro)]);
      }
      __syncthreads();
      if (tid == 0) {
        while (ld_bypass_u32(rel + (size_t)bid * 32) < tgt)
          __builtin_amdgcn_s_sleep(2);
      }
      __syncthreads();
    }

    // ============ Phase 2: scores + ctx/denom atomics ============
    su.p2.hw8[(tid & 7) * 64 + (tid >> 3)] = ld_bypass_f32(hwx + b * H_ + tid);
    __syncthreads();
    #pragma unroll
    for (int i = 0; i < 4; ++i) {
      int nn = wvx + i * 8;
      if (nn < nmax) {
        float p = 0.f;
        #pragma unroll
        for (int j = 0; j < 8; ++j)
          p += vreg[j] * fast_tanh(su.p2.hw8[j * 64 + lane] + b2f((u16)kvp[i][j]));
        p = wred_sum(p);
        if (lane == 0) su.p2.e[nn] = maskf[nn] * __expf(p);
      }
    }
    __syncthreads();
    if (wvx == 0) {
      float sp = (lane < nmax) ? su.p2.e[lane] : 0.f;
      sp = wred_sum(sp);
      if (lane == 0) atomicAdd(denom + cbuf * 32 + b, sp);
    }
    if (tid < 384) {
      float a0 = 0.f, a1 = 0.f;
      const u16* ep0 = enc_bf + ((size_t)(b * N_ + n0)) * D_ + 2 * tid;
      for (int nn = 0; nn < nmax; ++nn) {
        float ev = su.p2.e[nn];
        unsigned w = *(const unsigned*)(ep0 + (size_t)nn * D_);
        a0 += ev * b2f((u16)(w & 0xffffu));
        a1 += ev * b2f((u16)(w >> 16));
      }
      float* cp = ctxAcc + (size_t)cbuf * BD + b * D_ + 2 * tid;
      atomicAdd(cp, a0);
      atomicAdd(cp + 1, a1);
    }
    tgt += NBLK; gridbar(bars, rel, bid, tgt);   // bar2

    // ============ Phase 3: ctx stage + remaining MFMA + pointwise ============
    {
      const float* cp = ctxAcc + (size_t)cbuf * BD + (size_t)(b_base + bl) * D_;
      u32x4 ca[3][2]; float dv;
      ld6_1_bypass(cp + (kc0     ) * 8, cp + (kc0     ) * 8 + 4,
                   cp + (kc0 + 32) * 8, cp + (kc0 + 32) * 8 + 4,
                   cp + (kc0 + 64) * 8, cp + (kc0 + 64) * 8 + 4,
                   denom + cbuf * 32 + (b_base + bl),
                   ca[0][0], ca[0][1], ca[1][0], ca[1][1],
                   ca[2][0], ca[2][1], dv);
      float rdv = 1.f / dv;
      #pragma unroll
      for (int r2 = 0; r2 < 3; ++r2) {
        int kc = kc0 + r2 * 32;
        u32x4 pk;
        #pragma unroll
        for (int hh = 0; hh < 2; ++hh) {
          float x0 = __uint_as_float(ca[r2][hh][0]) * rdv;
          float x1 = __uint_as_float(ca[r2][hh][1]) * rdv;
          float x2 = __uint_as_float(ca[r2][hh][2]) * rdv;
          float x3 = __uint_as_float(ca[r2][hh][3]) * rdv;
          pk[hh * 2]     = (unsigned)f2b(x0) | ((unsigned)f2b(x1) << 16);
          pk[hh * 2 + 1] = (unsigned)f2b(x2) | ((unsigned)f2b(x3) << 16);
        }
        su.p3.ctx16[kc * 16 + bl] = pk;
      }
    }
    __syncthreads();
    #pragma unroll
    for (int i = 0; i < 5; ++i) {
      int ks = wvx * 5 + i;
      if (ks >= 16)
        gacc = __builtin_amdgcn_mfma_f32_16x16x32_bf16(
            *(const short8*)&su.p3.ctx16[((ks - 16) * 4 + kh) * 16 + n16], wf[i],
            gacc, 0, 0, 0);
    }
    *(f32x4*)&su.p3.part3[wvx][lane] = gacc;
    __syncthreads();
    if (tid < 256) {
      int lp = ((ro >> 2) << 4) | co;
      float v = su.p3.part3[0][lp][ro & 3] + su.p3.part3[1][lp][ro & 3]
              + su.p3.part3[2][lp][ro & 3] + su.p3.part3[3][lp][ro & 3]
              + su.p3.part3[4][lp][ro & 3] + su.p3.part3[5][lp][ro & 3]
              + su.p3.part3[6][lp][ro & 3] + su.p3.part3[7][lp][ro & 3];
      gpre[co][ro] = v + ge_pf;
    }
    __syncthreads();
    if (tid < 64) {
      int row = tid & 15, j = tid >> 4;
      float gI = gpre[j][row], gF = gpre[4 + j][row];
      float gG = gpre[8 + j][row], gO = gpre[12 + j][row];
      float co2 = cfl[j][row];
      float cn = sigm(gF) * co2 + sigm(gI) * fast_tanh(gG);
      float hn = sigm(gO) * fast_tanh(cn);
      cfl[j][row] = cn;
      int bgl = b_base + row, hidx = hx4 + j;
      st_bypass_u16(hx2 + (size_t)wb * BH + bgl * H_ + hidx, f2b(hn));
      h_hist[((size_t)(bgl * T_ + t)) * H_ + hidx] = f2b(hn);
      if (t == T_ - 1) {
        out_h[bgl * H_ + hidx] = hn;
        out_c[bgl * H_ + hidx] = cn;
      }
    }
    // ---- bar3 (arrive -> hidden work: zero next ctxAcc/denom buffers -> wait)
    tgt += NBLK;
    __syncthreads();
    if (tid == 0) {
      asm volatile("s_waitcnt vmcnt(0) lgkmcnt(0)" ::: "memory");
      __hip_atomic_fetch_add(bars + (size_t)(bid & 15) * 32, 1u,
                             __ATOMIC_RELAXED, __HIP_MEMORY_SCOPE_AGENT);
    }
    if (bid == 0) {
      if (tid == 0) { while (bar_sum16(bars) < tgt) __builtin_amdgcn_s_sleep(1); }
      __syncthreads();
      if (tid < NBLK) st_bypass_u32(rel + (size_t)tid * 32, tgt);
      if (tid < 96) st_bypass_f32(ctxAcc + (size_t)nbuf * BD + bid * 96 + tid, 0.f);
      if (tid < 32) st_bypass_f32(denom + nbuf * 32 + tid, 0.f);
    } else {
      if (tid < 96) st_bypass_f32(ctxAcc + (size_t)nbuf * BD + bid * 96 + tid, 0.f);
      __syncthreads();
      if (tid == 0) {
        while (ld_bypass_u32(rel + (size_t)bid * 32) < tgt)
          __builtin_amdgcn_s_sleep(2);
      }
      __syncthreads();
    }
  }
}

extern "C" void kernel_launch(void* const* d_in, const int* in_sizes, int n_in,
                              void* d_out, int out_size, void* d_ws, size_t ws_size,
                              hipStream_t stream) {
  const int*   x    = (const int*)d_in[0];
  const float* enc  = (const float*)d_in[1];
  const int*   mask = (const int*)d_in[2];
  const float* emb  = (const float*)d_in[3];
  const float* We   = (const float*)d_in[4];
  const float* Wh   = (const float*)d_in[5];
  const float* v    = (const float*)d_in[6];
  const float* Wih  = (const float*)d_in[7];
  const float* Whh  = (const float*)d_in[8];
  const float* bih  = (const float*)d_in[9];
  const float* bhh  = (const float*)d_in[10];
  const float* fcW  = (const float*)d_in[11];
  const float* fcb  = (const float*)d_in[12];
  const float* W2h  = (const float*)d_in[13];
  const float* b2h  = (const float*)d_in[14];
  const float* W2c  = (const float*)d_in[15];
  const float* b2c  = (const float*)d_in[16];
  float* out = (float*)d_out;

  char* ws = (char*)d_ws;
  u16* enc_bf = (u16*)(ws + O_ENCBF);
  u16* WhT    = (u16*)(ws + O_WHT);
  u16* WhhT   = (u16*)(ws + O_WHHT);
  u16* WihDT  = (u16*)(ws + O_WIHDT);
  u16* Ke     = (u16*)(ws + O_KE);
  u16* g_emb  = (u16*)(ws + O_GEMB);
  float* bsum = (float*)(ws + O_BSUM);
  float* cT   = (float*)(ws + O_CT);
  u16* h_hist = (u16*)(ws + O_HIST);
  u16* hx2    = (u16*)(ws + O_HX2);
  float* hwx  = (float*)(ws + O_HWX);
  float* ctxAcc = (float*)(ws + O_CTXA);
  float* denom  = (float*)(ws + O_DEN);
  unsigned* bars = (unsigned*)(ws + O_BARS);
  unsigned* rel  = (unsigned*)(ws + O_REL);
  float* out_h = out + (size_t)B_ * T_ * V_;
  float* out_c = out_h + B_ * H_;

  hipMemsetAsync(bars, 0, 2048, stream);
  hipMemsetAsync(rel, 0, 32768, stream);
  hipMemsetAsync(ctxAcc, 0, 196608, stream);
  hipMemsetAsync(denom, 0, 256, stream);
  conv_bf<<<1024, 256, 0, stream>>>(enc, enc_bf, B_ * N_ * D_);
  transpose_bf<<<dim3(8, 8), 256, 0, stream>>>(Wh, WhT, H_, H_);
  transpose_bf<<<dim3(32, 8), 256, 0, stream>>>(Whh, WhhT, H_, G4H);
  transpose_bf<<<dim3(32, 12), 256, 0, stream>>>(Wih + (size_t)E_ * G4H, WihDT, D_, G4H);
  bsum_k<<<8, 256, 0, stream>>>(bih, bhh, bsum, G4H);
  init_hc<<<32, 512, 0, stream>>>(enc, W2h, b2h, W2c, b2c, hx2, cT);
  // Ke = enc_bf @ We   (6272 x 512, K=768) -> bf16 row-major
  gemm2<0, 1, 0><<<dim3(4, 49), 256, 0, stream>>>(enc_bf, We, nullptr, (void*)Ke,
                                                  nullptr, B_ * N_, H_, D_, D_);
  // g_emb[t][col][b] = emb[x] @ Wih[:256] + bih + bhh  (4096 x 2048, K=256)
  gemm2<1, 3, 1><<<dim3(16, 32), 256, 0, stream>>>(emb, Wih, x, (void*)g_emb,
                                                   bsum, B_ * T_, G4H, E_, E_);
  recur8<<<NBLK, 512, 0, stream>>>(enc_bf, mask, Ke, WhT, v, WhhT, WihDT, g_emb,
                                   cT, hx2, hwx, ctxAcc, denom,
                                   h_hist, out_h, out_c, bars, rel);
  // logits = h_hist @ fcW + fcb  (4096 x 10000, K=512) -> f32
  gemm2<0, 0, 1><<<dim3(79, 32), 256, 0, stream>>>(h_hist, fcW, nullptr, (void*)out,
                                                   fcb, B_ * T_, V_, H_, H_);
}

// Round 15
// 2511.848 us; speedup vs baseline: 1.0518x; 1.0518x over previous
//
#include <hip/hip_runtime.h>

typedef unsigned short u16;
typedef __attribute__((ext_vector_type(8))) short short8;
typedef __attribute__((ext_vector_type(4))) float f32x4;
typedef __attribute__((ext_vector_type(4))) unsigned int u32x4;

#define B_  32
#define T_  128
#define N_  196
#define D_  768
#define E_  256
#define H_  512
#define V_  10000
#define G4H 2048
#define NBLK 256
#define BH  (B_ * H_)
#define BD  (B_ * D_)

// workspace offsets (bytes), all 256-aligned
#define O_ENCBF 0UL            // 9,633,792   enc bf16 [32][196][768]
#define O_WHT   9633792UL      // 524,288     WhT bf16 [col][k]
#define O_WHHT  10158080UL     // 2,097,152   WhhT [2048 col][512 k]
#define O_WIHDT 12255232UL     // 3,145,728   WihDT[2048 col][768 d]
#define O_KE    15400960UL     // 6,422,528   Ke bf16 [6272][512]
#define O_GEMB  21823488UL     // 16,777,216  g_emb bf16 [t][2048 col][32 b]
#define O_BSUM  38600704UL     // 8,192       bih+bhh
#define O_CT    38608896UL     // 65,536      c0 f32 [32][512]
#define O_HIST  38674432UL     // 4,194,304   h_hist bf16 [b*T+t][512]
#define O_HX2   42868736UL     // 65,536      h bf16 [2][32][512]
#define O_HWX   42934272UL     // 65,536      hw f32 [32][512]
#define O_CTXA  42999808UL     // 196,608     ctxAcc f32 [2][32][768]
#define O_DEN   43196416UL     // 256         denom f32 [2][32]
#define O_BARS  43196672UL     // 2,048       16 arrival lines x 128B
#define O_REL   43198720UL     // 32,768      256 release lines x 128B

__device__ __forceinline__ float b2f(u16 u) {
  union { unsigned i; float f; } c; c.i = ((unsigned)u) << 16; return c.f;
}
__device__ __forceinline__ u16 f2b(float f) {   // RNE f32->bf16
  unsigned u = __float_as_uint(f);
  unsigned r = (u + 0x7fffu + ((u >> 16) & 1u)) >> 16;
  return (u16)r;
}
__device__ __forceinline__ float fast_tanh(float x) {
  float e = __expf(2.f * x);
  return 1.f - 2.f * __builtin_amdgcn_rcpf(e + 1.f);
}
__device__ __forceinline__ float sigm(float x) {
  return __builtin_amdgcn_rcpf(1.f + __expf(-x));
}
__device__ __forceinline__ float wred_sum(float x) {
  #pragma unroll
  for (int o = 32; o; o >>= 1) x += __shfl_xor(x, o, 64);
  return x;
}

// ---- L2-bypass (device-coherent) ops ----
__device__ __forceinline__ float ld_bypass_f32(const float* p) {
  float v;
  asm volatile("global_load_dword %0, %1, off sc0 sc1\n\ts_waitcnt vmcnt(0)"
               : "=v"(v) : "v"(p) : "memory");
  return v;
}
__device__ __forceinline__ unsigned ld_bypass_u32(const unsigned* p) {
  unsigned v;
  asm volatile("global_load_dword %0, %1, off sc0 sc1\n\ts_waitcnt vmcnt(0)"
               : "=v"(v) : "v"(p) : "memory");
  return v;
}
__device__ __forceinline__ void ld2_bypass(const void* p0, const void* p1,
                                           u32x4& a, u32x4& b) {
  asm volatile(
    "global_load_dwordx4 %0, %2, off sc0 sc1\n\t"
    "global_load_dwordx4 %1, %3, off sc0 sc1\n\t"
    "s_waitcnt vmcnt(0)"
    : "=&v"(a), "=&v"(b) : "v"(p0), "v"(p1) : "memory");
}
// 6 x4-loads (ctxAcc f32) + 1 f32 (denom), single wait
__device__ __forceinline__ void ld6_1_bypass(
    const void* p0, const void* p1, const void* p2, const void* p3,
    const void* p4, const void* p5, const void* pd,
    u32x4& a, u32x4& b, u32x4& c, u32x4& d, u32x4& e, u32x4& f, float& dv) {
  asm volatile(
    "global_load_dwordx4 %0, %7, off sc0 sc1\n\t"
    "global_load_dwordx4 %1, %8, off sc0 sc1\n\t"
    "global_load_dwordx4 %2, %9, off sc0 sc1\n\t"
    "global_load_dwordx4 %3, %10, off sc0 sc1\n\t"
    "global_load_dwordx4 %4, %11, off sc0 sc1\n\t"
    "global_load_dwordx4 %5, %12, off sc0 sc1\n\t"
    "global_load_dword %6, %13, off sc0 sc1\n\t"
    "s_waitcnt vmcnt(0)"
    : "=&v"(a), "=&v"(b), "=&v"(c), "=&v"(d), "=&v"(e), "=&v"(f), "=&v"(dv)
    : "v"(p0), "v"(p1), "v"(p2), "v"(p3), "v"(p4), "v"(p5), "v"(pd)
    : "memory");
}
__device__ __forceinline__ void st_bypass_f32(float* p, float v) {
  asm volatile("global_store_dword %0, %1, off sc0 sc1" :: "v"(p), "v"(v) : "memory");
}
__device__ __forceinline__ void st_bypass_u32(unsigned* p, unsigned v) {
  asm volatile("global_store_dword %0, %1, off sc0 sc1" :: "v"(p), "v"(v) : "memory");
}
__device__ __forceinline__ void st_bypass_u16(u16* p, u16 v) {
  unsigned vv = v;
  asm volatile("global_store_short %0, %1, off sc0 sc1" :: "v"(p), "v"(vv) : "memory");
}

__device__ __forceinline__ unsigned bar_sum16(const unsigned* p) {
  unsigned a0,a1,a2,a3,a4,a5,a6,a7,a8,a9,a10,a11,a12,a13,a14,a15;
  asm volatile(
    "global_load_dword %0, %16, off sc0 sc1\n\t"
    "global_load_dword %1, %16, off offset:128 sc0 sc1\n\t"
    "global_load_dword %2, %16, off offset:256 sc0 sc1\n\t"
    "global_load_dword %3, %16, off offset:384 sc0 sc1\n\t"
    "global_load_dword %4, %16, off offset:512 sc0 sc1\n\t"
    "global_load_dword %5, %16, off offset:640 sc0 sc1\n\t"
    "global_load_dword %6, %16, off offset:768 sc0 sc1\n\t"
    "global_load_dword %7, %16, off offset:896 sc0 sc1\n\t"
    "global_load_dword %8, %16, off offset:1024 sc0 sc1\n\t"
    "global_load_dword %9, %16, off offset:1152 sc0 sc1\n\t"
    "global_load_dword %10, %16, off offset:1280 sc0 sc1\n\t"
    "global_load_dword %11, %16, off offset:1408 sc0 sc1\n\t"
    "global_load_dword %12, %16, off offset:1536 sc0 sc1\n\t"
    "global_load_dword %13, %16, off offset:1664 sc0 sc1\n\t"
    "global_load_dword %14, %16, off offset:1792 sc0 sc1\n\t"
    "global_load_dword %15, %16, off offset:1920 sc0 sc1\n\t"
    "s_waitcnt vmcnt(0)"
    : "=&v"(a0), "=&v"(a1), "=&v"(a2), "=&v"(a3), "=&v"(a4), "=&v"(a5),
      "=&v"(a6), "=&v"(a7), "=&v"(a8), "=&v"(a9), "=&v"(a10), "=&v"(a11),
      "=&v"(a12), "=&v"(a13), "=&v"(a14), "=&v"(a15)
    : "v"(p) : "memory");
  return ((a0+a1)+(a2+a3)) + ((a4+a5)+(a6+a7)) +
         ((a8+a9)+(a10+a11)) + ((a12+a13)+(a14+a15));
}

// master-detect + private-line broadcast grid barrier
__device__ __forceinline__ void gridbar(unsigned* bars, unsigned* rel,
                                        int bid, unsigned target) {
  __syncthreads();
  if (bid == 0) {
    if (threadIdx.x == 0) {
      asm volatile("s_waitcnt vmcnt(0) lgkmcnt(0)" ::: "memory");
      __hip_atomic_fetch_add(bars, 1u, __ATOMIC_RELAXED, __HIP_MEMORY_SCOPE_AGENT);
      while (bar_sum16(bars) < target) __builtin_amdgcn_s_sleep(1);
    }
    __syncthreads();
    if (threadIdx.x < NBLK) st_bypass_u32(rel + (size_t)threadIdx.x * 32, target);
  } else {
    if (threadIdx.x == 0) {
      asm volatile("s_waitcnt vmcnt(0) lgkmcnt(0)" ::: "memory");
      __hip_atomic_fetch_add(bars + (size_t)(bid & 15) * 32, 1u,
                             __ATOMIC_RELAXED, __HIP_MEMORY_SCOPE_AGENT);
      while (ld_bypass_u32(rel + (size_t)bid * 32) < target)
        __builtin_amdgcn_s_sleep(2);
    }
    __syncthreads();
  }
}

// ---------------- prep kernels ----------------

__global__ void conv_bf(const float* __restrict__ in, u16* __restrict__ out, int n) {
  int i = blockIdx.x * blockDim.x + threadIdx.x;
  int st = gridDim.x * blockDim.x;
  for (; i < n; i += st) out[i] = f2b(in[i]);
}

__global__ void bsum_k(const float* __restrict__ a, const float* __restrict__ b,
                       float* __restrict__ o, int n) {
  int i = blockIdx.x * blockDim.x + threadIdx.x;
  if (i < n) o[i] = a[i] + b[i];
}

// out[c][r] = bf16(in[r][c]); in is R x C
__global__ void transpose_bf(const float* __restrict__ in, u16* __restrict__ out, int R, int C) {
  __shared__ float tl[64][65];
  int tid = threadIdx.x;
  int tc0 = blockIdx.x * 64, tr0 = blockIdx.y * 64;
  int cc = tid & 63;
  for (int rr = tid >> 6; rr < 64; rr += 4) {
    int rg = tr0 + rr, cg = tc0 + cc;
    tl[rr][cc] = (rg < R && cg < C) ? in[(size_t)rg * C + cg] : 0.f;
  }
  __syncthreads();
  int rr = tid & 63;
  for (int c2 = tid >> 6; c2 < 64; c2 += 4) {
    int cg = tc0 + c2, rg = tr0 + rr;
    if (cg < C && rg < R) out[(size_t)cg * R + rg] = f2b(tl[rr][c2]);
  }
}

// h0/c0 (writes h bf16 into exchange buffer 0)
__global__ __launch_bounds__(512) void init_hc(
    const float* __restrict__ enc, const float* __restrict__ W2h,
    const float* __restrict__ b2h, const float* __restrict__ W2c,
    const float* __restrict__ b2c, u16* __restrict__ hx2, float* __restrict__ cT)
{
  __shared__ float pool[D_];
  int b = blockIdx.x, tid = threadIdx.x;
  for (int d = tid; d < D_; d += 512) {
    float s = 0.f;
    const float* ep = enc + (size_t)b * N_ * D_ + d;
    for (int n = 0; n < N_; ++n) s += ep[(size_t)n * D_];
    pool[d] = s * (1.f / 196.f);
  }
  __syncthreads();
  float a = b2h[tid], a2 = b2c[tid];
  #pragma unroll 4
  for (int d = 0; d < D_; ++d) {
    float pv = pool[d];
    a  += pv * W2h[d * H_ + tid];
    a2 += pv * W2c[d * H_ + tid];
  }
  hx2[b * H_ + tid] = f2b(fast_tanh(a));
  cT[b * H_ + tid] = fast_tanh(a2);
}

// ---------------- MFMA GEMM ----------------
// AMODE: 0 = A bf16; 1 = A f32 gathered via xidx
// OUTMODE: 0 = f32 row-major; 1 = bf16 row-major; 3 = bf16 scatter [t][col][b]
template<int AMODE, int OUTMODE, int BIAS>
__global__ __launch_bounds__(256) void gemm2(
    const void* __restrict__ Av, const float* __restrict__ Bf,
    const int* __restrict__ xidx, void* __restrict__ Cv,
    const float* __restrict__ bias, int M, int N, int K, int lda)
{
  __shared__ __align__(16) u16 Al[128][72];
  __shared__ __align__(16) u16 Bl[128][72];
  const int tid = threadIdx.x;
  const int tm0 = blockIdx.y * 128, tn0 = blockIdx.x * 128;
  const int wv = tid >> 6, lane = tid & 63;
  const int wr = wv >> 1, wc = wv & 1;
  f32x4 acc[4][4] = {};
  const int r = tid >> 1, cb = (tid & 1) * 32;
  const int bkr = tid >> 5;
  const int bnc = (tid & 31) * 4;
  for (int k0 = 0; k0 < K; k0 += 64) {
    int rm = tm0 + r; if (rm >= M) rm = M - 1;
    if (AMODE == 0) {
      const u16* gp = (const u16*)Av + (size_t)rm * lda + k0 + cb;
      #pragma unroll
      for (int u = 0; u < 4; ++u)
        *(short8*)&Al[r][cb + u * 8] = *(const short8*)(gp + u * 8);
    } else {
      const float* gp = (const float*)Av + (size_t)xidx[rm] * lda + k0 + cb;
      #pragma unroll
      for (int u = 0; u < 4; ++u) {
        f32x4 a0 = *(const f32x4*)(gp + u * 8);
        f32x4 a1 = *(const f32x4*)(gp + u * 8 + 4);
        Al[r][cb + u * 8 + 0] = f2b(a0[0]); Al[r][cb + u * 8 + 1] = f2b(a0[1]);
        Al[r][cb + u * 8 + 2] = f2b(a0[2]); Al[r][cb + u * 8 + 3] = f2b(a0[3]);
        Al[r][cb + u * 8 + 4] = f2b(a1[0]); Al[r][cb + u * 8 + 5] = f2b(a1[1]);
        Al[r][cb + u * 8 + 6] = f2b(a1[2]); Al[r][cb + u * 8 + 7] = f2b(a1[3]);
      }
    }
    {
      int ncc = tn0 + bnc; if (ncc > N - 4) ncc = N - 4;
      #pragma unroll
      for (int u = 0; u < 8; ++u) {
        int kr = bkr + u * 8;
        const float* bp = Bf + (size_t)(k0 + kr) * N + ncc;
        f32x4 bv = *(const f32x4*)bp;
        #pragma unroll
        for (int j = 0; j < 4; ++j) Bl[bnc + j][kr] = f2b(bv[j]);
      }
    }
    __syncthreads();
    #pragma unroll
    for (int kk = 0; kk < 64; kk += 32) {
      short8 af[4], bfv[4];
      #pragma unroll
      for (int i = 0; i < 4; ++i)
        af[i] = *(const short8*)&Al[wr * 64 + i * 16 + (lane & 15)][kk + (lane >> 4) * 8];
      #pragma unroll
      for (int j = 0; j < 4; ++j)
        bfv[j] = *(const short8*)&Bl[wc * 64 + j * 16 + (lane & 15)][kk + (lane >> 4) * 8];
      #pragma unroll
      for (int i = 0; i < 4; ++i)
        #pragma unroll
        for (int j = 0; j < 4; ++j)
          acc[i][j] = __builtin_amdgcn_mfma_f32_16x16x32_bf16(af[i], bfv[j], acc[i][j], 0, 0, 0);
    }
    __syncthreads();
  }
  #pragma unroll
  for (int i = 0; i < 4; ++i) {
    int row0 = tm0 + wr * 64 + i * 16 + (lane >> 4) * 4;
    #pragma unroll
    for (int j = 0; j < 4; ++j) {
      int col = tn0 + wc * 64 + j * 16 + (lane & 15);
      if (col < N) {
        float bs = BIAS ? bias[col] : 0.f;
        #pragma unroll
        for (int rr2 = 0; rr2 < 4; ++rr2) {
          int row = row0 + rr2;
          if (row < M) {
            float val = acc[i][j][rr2] + bs;
            if (OUTMODE == 0) ((float*)Cv)[(size_t)row * N + col] = val;
            else if (OUTMODE == 1) ((u16*)Cv)[(size_t)row * N + col] = f2b(val);
            else {
              int tt = row & 127, bb = row >> 7;
              ((u16*)Cv)[((size_t)tt * G4H + col) * 32 + bb] = f2b(val);
            }
          }
        }
      }
    }
  }
}

// ---------------- persistent 3-phase recurrent kernel ----------------
// 256 blocks x 512.
// Attention role: (b = bid>>3, s8 = bid&7): scores for n-slice s8.
// hw role (balanced): every block computes hw tile [16b x 4c] via VALU with
//   register-resident Wh column-slice; wave = K-slice.
// Gate role: (bh = bid>>7, hb4 = bid&127): 16 gate cols for 16 b's, MFMA.
__global__ __launch_bounds__(512, 1) void recur9(
    const u16* __restrict__ enc_bf, const int* __restrict__ mask,
    const u16* __restrict__ Ke, const u16* __restrict__ WhT,
    const float* __restrict__ vvec, const u16* __restrict__ WhhT,
    const u16* __restrict__ WihDT, const u16* __restrict__ g_emb,
    const float* __restrict__ cT0,
    u16* hx2, float* hwx, float* ctxAcc, float* denom,
    u16* h_hist, float* out_h, float* out_c, unsigned* bars, unsigned* rel)
{
  __shared__ u32x4 hst16[64 * 16];       // h bf16 chunks [kc][16b], 16KB
  __shared__ union {
    struct { float part1[8][64]; } p1;                        // 2KB
    struct { float hw8[512]; float e[32]; } p2;               // 2.2KB
    struct { u32x4 ctx16[96 * 16]; f32x4 part3[8][69]; } p3;  // ~33.4KB
  } su;
  __shared__ float gpre[16][16];
  __shared__ float cfl[4][16];     // persistent c state
  __shared__ float maskf[32];      // persistent mask slice

  const int bid = blockIdx.x, tid = threadIdx.x;
  const int lane = tid & 63, wvx = tid >> 6;
  // attention role
  const int b = bid >> 3, s8 = bid & 7;
  const int n0 = s8 * 25;
  const int nmax = min(25, N_ - n0);
  // gate role
  const int bh = bid >> 7, hb4 = bid & 127;
  const int b_base = bh * 16, hx4 = hb4 * 4;
  const int n16 = lane & 15, kh = lane >> 4;
  const int gcol = (n16 >> 2) * H_ + hx4 + (n16 & 3);
  // hw role (balanced): thread = (b16, c4); wave = K-slice hks
  const int hb16 = tid & 15, hc4 = (tid >> 4) & 3, hks = tid >> 6;
  const int hwc = hb4 * 4 + hc4;
  // staging role
  const int bl = tid & 15, kc0 = tid >> 4;   // kc0 in [0,32)
  // readout role (tid<256)
  const int ro = tid & 15, co = tid >> 4;

  float vreg[8];
  #pragma unroll
  for (int j = 0; j < 8; ++j) vreg[j] = vvec[lane * 8 + j];
  if (tid < nmax) maskf[tid] = (mask[b * N_ + n0 + tid] == 0) ? 0.f : 1.f;
  if (tid < 64) cfl[tid >> 4][tid & 15] =
      cT0[(b_base + (tid & 15)) * H_ + hx4 + (tid >> 4)];

  // loop-invariant register weights
  short8 wf[5];                 // gate-weight fragments
  #pragma unroll
  for (int i = 0; i < 5; ++i) {
    int ks = wvx * 5 + i;
    if (ks < 16) wf[i] = *(const short8*)(WhhT + (size_t)gcol * H_ + ks * 32 + kh * 8);
    else         wf[i] = *(const short8*)(WihDT + (size_t)gcol * D_ + (ks - 16) * 32 + kh * 8);
  }
  short8 wh8[8];                // Wh column-slice for hw role (col hwc, K hks*64..+64)
  #pragma unroll
  for (int i = 0; i < 8; ++i)
    wh8[i] = *(const short8*)(WhT + (size_t)hwc * H_ + hks * 64 + i * 8);
  short8 kvp[4];                // Ke rows for this lane / n-slice
  #pragma unroll
  for (int i = 0; i < 4; ++i) {
    int nn = wvx + i * 8; if (nn >= nmax) nn = nmax - 1;
    kvp[i] = *(const short8*)(Ke + ((size_t)(b * N_ + n0 + nn)) * H_ + lane * 8);
  }
  __syncthreads();

  unsigned tgt = 0;
  for (int t = 0; t < T_; ++t) {
    const int rb = t & 1, wb = rb ^ 1;
    const int cbuf = t & 1, nbuf = cbuf ^ 1;
    // ============ Phase 1: stage hst16; hw tiles (balanced VALU) ============
    {
      const u16* hp = hx2 + (size_t)rb * BH + (b_base + bl) * H_;
      u32x4 v0, v1;
      ld2_bypass(hp + kc0 * 8, hp + (kc0 + 32) * 8, v0, v1);
      hst16[(kc0     ) * 16 + bl] = v0;
      hst16[(kc0 + 32) * 16 + bl] = v1;
    }
    __syncthreads();
    {
      float acc = 0.f;
      #pragma unroll
      for (int i = 0; i < 8; ++i) {
        short8 hb8 = *(const short8*)&hst16[(hks * 8 + i) * 16 + hb16];
        #pragma unroll
        for (int j = 0; j < 8; ++j)
          acc += b2f((u16)wh8[i][j]) * b2f((u16)hb8[j]);
      }
      su.p1.part1[hks][hc4 * 16 + hb16] = acc;
    }
    __syncthreads();
    if (tid < 64) {
      float s = 0.f;
      #pragma unroll
      for (int w = 0; w < 8; ++w) s += su.p1.part1[w][tid];
      st_bypass_f32(hwx + (size_t)(b_base + (tid & 15)) * H_ + hb4 * 4 + (tid >> 4), s);
    }
    // ---- bar1 (arrive -> hidden work: Whh-half MFMA + g_emb prefetch -> wait)
    tgt += NBLK;
    f32x4 gacc = {0.f, 0.f, 0.f, 0.f};
    float ge_pf = 0.f;
    __syncthreads();
    if (tid == 0) {
      asm volatile("s_waitcnt vmcnt(0) lgkmcnt(0)" ::: "memory");
      __hip_atomic_fetch_add(bars + (size_t)(bid & 15) * 32, 1u,
                             __ATOMIC_RELAXED, __HIP_MEMORY_SCOPE_AGENT);
    }
    if (bid == 0) {
      if (tid == 0) { while (bar_sum16(bars) < tgt) __builtin_amdgcn_s_sleep(1); }
      __syncthreads();
      if (tid < NBLK) st_bypass_u32(rel + (size_t)tid * 32, tgt);
      #pragma unroll
      for (int i = 0; i < 5; ++i) {
        int ks = wvx * 5 + i;
        if (ks < 16)
          gacc = __builtin_amdgcn_mfma_f32_16x16x32_bf16(
              *(const short8*)&hst16[(ks * 4 + kh) * 16 + n16], wf[i], gacc, 0, 0, 0);
      }
      if (tid < 256) {
        int gco = (co >> 2) * H_ + hx4 + (co & 3);
        ge_pf = b2f(g_emb[((size_t)t * G4H + gco) * 32 + (b_base + ro)]);
      }
    } else {
      #pragma unroll
      for (int i = 0; i < 5; ++i) {
        int ks = wvx * 5 + i;
        if (ks < 16)
          gacc = __builtin_amdgcn_mfma_f32_16x16x32_bf16(
              *(const short8*)&hst16[(ks * 4 + kh) * 16 + n16], wf[i], gacc, 0, 0, 0);
      }
      if (tid < 256) {
        int gco = (co >> 2) * H_ + hx4 + (co & 3);
        ge_pf = b2f(g_emb[((size_t)t * G4H + gco) * 32 + (b_base + ro)]);
      }
      __syncthreads();
      if (tid == 0) {
        while (ld_bypass_u32(rel + (size_t)bid * 32) < tgt)
          __builtin_amdgcn_s_sleep(2);
      }
      __syncthreads();
    }

    // ============ Phase 2: scores + ctx/denom atomics ============
    su.p2.hw8[(tid & 7) * 64 + (tid >> 3)] = ld_bypass_f32(hwx + b * H_ + tid);
    if (tid >= 25 && tid < 32) su.p2.e[tid] = 0.f;   // zero-pad tail
    __syncthreads();
    #pragma unroll
    for (int i = 0; i < 4; ++i) {
      int nn = wvx + i * 8;
      if (nn < nmax) {
        float p = 0.f;
        #pragma unroll
        for (int j = 0; j < 8; ++j)
          p += vreg[j] * fast_tanh(su.p2.hw8[j * 64 + lane] + b2f((u16)kvp[i][j]));
        p = wred_sum(p);
        if (lane == 0) su.p2.e[nn] = maskf[nn] * __expf(p);
      }
    }
    __syncthreads();
    if (wvx == 0) {
      float sp = (lane < 25) ? su.p2.e[lane] : 0.f;
      sp = wred_sum(sp);
      if (lane == 0) atomicAdd(denom + cbuf * 32 + b, sp);
    }
    if (tid < 384) {
      float a0 = 0.f, a1 = 0.f;
      const u16* ep0 = enc_bf + ((size_t)(b * N_ + n0)) * D_ + 2 * tid;
      #pragma unroll
      for (int nn = 0; nn < 25; ++nn) {
        int nn_c = (nn < nmax) ? nn : 0;      // clamp addr; e=0 for pad
        float ev = su.p2.e[nn];
        unsigned w = *(const unsigned*)(ep0 + (size_t)nn_c * D_);
        a0 += ev * b2f((u16)(w & 0xffffu));
        a1 += ev * b2f((u16)(w >> 16));
      }
      float* cp = ctxAcc + (size_t)cbuf * BD + b * D_ + 2 * tid;
      atomicAdd(cp, a0);
      atomicAdd(cp + 1, a1);
    }
    tgt += NBLK; gridbar(bars, rel, bid, tgt);   // bar2

    // ============ Phase 3: ctx stage + remaining MFMA + pointwise ============
    {
      const float* cp = ctxAcc + (size_t)cbuf * BD + (size_t)(b_base + bl) * D_;
      u32x4 ca[3][2]; float dv;
      ld6_1_bypass(cp + (kc0     ) * 8, cp + (kc0     ) * 8 + 4,
                   cp + (kc0 + 32) * 8, cp + (kc0 + 32) * 8 + 4,
                   cp + (kc0 + 64) * 8, cp + (kc0 + 64) * 8 + 4,
                   denom + cbuf * 32 + (b_base + bl),
                   ca[0][0], ca[0][1], ca[1][0], ca[1][1],
                   ca[2][0], ca[2][1], dv);
      float rdv = 1.f / dv;
      #pragma unroll
      for (int r2 = 0; r2 < 3; ++r2) {
        int kc = kc0 + r2 * 32;
        u32x4 pk;
        #pragma unroll
        for (int hh = 0; hh < 2; ++hh) {
          float x0 = __uint_as_float(ca[r2][hh][0]) * rdv;
          float x1 = __uint_as_float(ca[r2][hh][1]) * rdv;
          float x2 = __uint_as_float(ca[r2][hh][2]) * rdv;
          float x3 = __uint_as_float(ca[r2][hh][3]) * rdv;
          pk[hh * 2]     = (unsigned)f2b(x0) | ((unsigned)f2b(x1) << 16);
          pk[hh * 2 + 1] = (unsigned)f2b(x2) | ((unsigned)f2b(x3) << 16);
        }
        su.p3.ctx16[kc * 16 + bl] = pk;
      }
    }
    __syncthreads();
    #pragma unroll
    for (int i = 0; i < 5; ++i) {
      int ks = wvx * 5 + i;
      if (ks >= 16)
        gacc = __builtin_amdgcn_mfma_f32_16x16x32_bf16(
            *(const short8*)&su.p3.ctx16[((ks - 16) * 4 + kh) * 16 + n16], wf[i],
            gacc, 0, 0, 0);
    }
    *(f32x4*)&su.p3.part3[wvx][lane] = gacc;
    __syncthreads();
    if (tid < 256) {
      int lp = ((ro >> 2) << 4) | co;
      float v = su.p3.part3[0][lp][ro & 3] + su.p3.part3[1][lp][ro & 3]
              + su.p3.part3[2][lp][ro & 3] + su.p3.part3[3][lp][ro & 3]
              + su.p3.part3[4][lp][ro & 3] + su.p3.part3[5][lp][ro & 3]
              + su.p3.part3[6][lp][ro & 3] + su.p3.part3[7][lp][ro & 3];
      gpre[co][ro] = v + ge_pf;
    }
    __syncthreads();
    if (tid < 64) {
      int row = tid & 15, j = tid >> 4;
      float gI = gpre[j][row], gF = gpre[4 + j][row];
      float gG = gpre[8 + j][row], gO = gpre[12 + j][row];
      float co2 = cfl[j][row];
      float cn = sigm(gF) * co2 + sigm(gI) * fast_tanh(gG);
      float hn = sigm(gO) * fast_tanh(cn);
      cfl[j][row] = cn;
      int bgl = b_base + row, hidx = hx4 + j;
      st_bypass_u16(hx2 + (size_t)wb * BH + bgl * H_ + hidx, f2b(hn));
      h_hist[((size_t)(bgl * T_ + t)) * H_ + hidx] = f2b(hn);
      if (t == T_ - 1) {
        out_h[bgl * H_ + hidx] = hn;
        out_c[bgl * H_ + hidx] = cn;
      }
    }
    // ---- bar3 (arrive -> hidden work: zero next ctxAcc/denom buffers -> wait)
    tgt += NBLK;
    __syncthreads();
    if (tid == 0) {
      asm volatile("s_waitcnt vmcnt(0) lgkmcnt(0)" ::: "memory");
      __hip_atomic_fetch_add(bars + (size_t)(bid & 15) * 32, 1u,
                             __ATOMIC_RELAXED, __HIP_MEMORY_SCOPE_AGENT);
    }
    if (bid == 0) {
      if (tid == 0) { while (bar_sum16(bars) < tgt) __builtin_amdgcn_s_sleep(1); }
      __syncthreads();
      if (tid < NBLK) st_bypass_u32(rel + (size_t)tid * 32, tgt);
      if (tid < 96) st_bypass_f32(ctxAcc + (size_t)nbuf * BD + bid * 96 + tid, 0.f);
      if (tid < 32) st_bypass_f32(denom + nbuf * 32 + tid, 0.f);
    } else {
      if (tid < 96) st_bypass_f32(ctxAcc + (size_t)nbuf * BD + bid * 96 + tid, 0.f);
      __syncthreads();
      if (tid == 0) {
        while (ld_bypass_u32(rel + (size_t)bid * 32) < tgt)
          __builtin_amdgcn_s_sleep(2);
      }
      __syncthreads();
    }
  }
}

extern "C" void kernel_launch(void* const* d_in, const int* in_sizes, int n_in,
                              void* d_out, int out_size, void* d_ws, size_t ws_size,
                              hipStream_t stream) {
  const int*   x    = (const int*)d_in[0];
  const float* enc  = (const float*)d_in[1];
  const int*   mask = (const int*)d_in[2];
  const float* emb  = (const float*)d_in[3];
  const float* We   = (const float*)d_in[4];
  const float* Wh   = (const float*)d_in[5];
  const float* v    = (const float*)d_in[6];
  const float* Wih  = (const float*)d_in[7];
  const float* Whh  = (const float*)d_in[8];
  const float* bih  = (const float*)d_in[9];
  const float* bhh  = (const float*)d_in[10];
  const float* fcW  = (const float*)d_in[11];
  const float* fcb  = (const float*)d_in[12];
  const float* W2h  = (const float*)d_in[13];
  const float* b2h  = (const float*)d_in[14];
  const float* W2c  = (const float*)d_in[15];
  const float* b2c  = (const float*)d_in[16];
  float* out = (float*)d_out;

  char* ws = (char*)d_ws;
  u16* enc_bf = (u16*)(ws + O_ENCBF);
  u16* WhT    = (u16*)(ws + O_WHT);
  u16* WhhT   = (u16*)(ws + O_WHHT);
  u16* WihDT  = (u16*)(ws + O_WIHDT);
  u16* Ke     = (u16*)(ws + O_KE);
  u16* g_emb  = (u16*)(ws + O_GEMB);
  float* bsum = (float*)(ws + O_BSUM);
  float* cT   = (float*)(ws + O_CT);
  u16* h_hist = (u16*)(ws + O_HIST);
  u16* hx2    = (u16*)(ws + O_HX2);
  float* hwx  = (float*)(ws + O_HWX);
  float* ctxAcc = (float*)(ws + O_CTXA);
  float* denom  = (float*)(ws + O_DEN);
  unsigned* bars = (unsigned*)(ws + O_BARS);
  unsigned* rel  = (unsigned*)(ws + O_REL);
  float* out_h = out + (size_t)B_ * T_ * V_;
  float* out_c = out_h + B_ * H_;

  hipMemsetAsync(bars, 0, 2048, stream);
  hipMemsetAsync(rel, 0, 32768, stream);
  hipMemsetAsync(ctxAcc, 0, 196608, stream);
  hipMemsetAsync(denom, 0, 256, stream);
  conv_bf<<<1024, 256, 0, stream>>>(enc, enc_bf, B_ * N_ * D_);
  transpose_bf<<<dim3(8, 8), 256, 0, stream>>>(Wh, WhT, H_, H_);
  transpose_bf<<<dim3(32, 8), 256, 0, stream>>>(Whh, WhhT, H_, G4H);
  transpose_bf<<<dim3(32, 12), 256, 0, stream>>>(Wih + (size_t)E_ * G4H, WihDT, D_, G4H);
  bsum_k<<<8, 256, 0, stream>>>(bih, bhh, bsum, G4H);
  init_hc<<<32, 512, 0, stream>>>(enc, W2h, b2h, W2c, b2c, hx2, cT);
  // Ke = enc_bf @ We   (6272 x 512, K=768) -> bf16 row-major
  gemm2<0, 1, 0><<<dim3(4, 49), 256, 0, stream>>>(enc_bf, We, nullptr, (void*)Ke,
                                                  nullptr, B_ * N_, H_, D_, D_);
  // g_emb[t][col][b] = emb[x] @ Wih[:256] + bih + bhh  (4096 x 2048, K=256)
  gemm2<1, 3, 1><<<dim3(16, 32), 256, 0, stream>>>(emb, Wih, x, (void*)g_emb,
                                                   bsum, B_ * T_, G4H, E_, E_);
  recur9<<<NBLK, 512, 0, stream>>>(enc_bf, mask, Ke, WhT, v, WhhT, WihDT, g_emb,
                                   cT, hx2, hwx, ctxAcc, denom,
                                   h_hist, out_h, out_c, bars, rel);
  // logits = h_hist @ fcW + fcb  (4096 x 10000, K=512) -> f32
  gemm2<0, 0, 1><<<dim3(79, 32), 256, 0, stream>>>(h_hist, fcW, nullptr, (void*)out,
                                                   fcb, B_ * T_, V_, H_, H_);
}